// Round 5
// baseline (38.964 us; speedup 1.0000x reference)
//
#include <hip/hip_runtime.h>

#define B_   4
#define L_   1024
#define D_   16
#define H_   32
#define TAU_ 64
#define EMB_ 8
#define JT_  128   // j-tile width (2 cols/thread -> float2 stores, 512 B/wave)
#define AEP_ 33    // ae_lds stride

// ---------------------------------------------------------------------------
// Kernel 1: precompute (unchanged)
//   ai[b,l,h] = x[b,l,:] @ W1[0:16, h]
//   aj[b,l,h] = x[b,l,:] @ W1[16:32, h]
//   ae[t,h]   = dt_table[t,:] @ W1[32:40, h] + b1[h]
// ---------------------------------------------------------------------------
__global__ __launch_bounds__(256) void precompute_kernel(
    const float* __restrict__ x, const float* __restrict__ dtt,
    const float* __restrict__ W1, const float* __restrict__ b1,
    float* __restrict__ ai, float* __restrict__ aj, float* __restrict__ ae)
{
    const int id = blockIdx.x * 256 + threadIdx.x;
    const int NA = B_ * L_ * H_;
    if (id < NA) {
        const int h   = id & (H_ - 1);
        const int row = id >> 5;                 // b*L + l
        const float4* xr4 = (const float4*)(x + row * D_);
        const float4 v0 = xr4[0], v1 = xr4[1], v2 = xr4[2], v3 = xr4[3];
        const float xv[D_] = {v0.x, v0.y, v0.z, v0.w, v1.x, v1.y, v1.z, v1.w,
                              v2.x, v2.y, v2.z, v2.w, v3.x, v3.y, v3.z, v3.w};
        float s1 = 0.f, s2 = 0.f;
#pragma unroll
        for (int d = 0; d < D_; ++d) {
            s1 = fmaf(xv[d], W1[d * H_ + h], s1);
            s2 = fmaf(xv[d], W1[(D_ + d) * H_ + h], s2);
        }
        ai[id] = s1;
        aj[id] = s2;
    } else {
        const int k = id - NA;
        if (k < (TAU_ + 1) * H_) {
            const int h = k & (H_ - 1);
            const int t = k >> 5;
            float s = b1[h];
#pragma unroll
            for (int e = 0; e < EMB_; ++e)
                s = fmaf(dtt[t * EMB_ + e], W1[(2 * D_ + e) * H_ + h], s);
            ae[k] = s;
        }
    }
}

// ---------------------------------------------------------------------------
// Kernel 2: bias kernel, wide-store edition.
// Tile 64 i x 128 j; 256 thr = 4 waves; wave w owns rows i0+w*16..+15.
// Each thread owns TWO adjacent j columns (jp, jp+1): float2 plain stores
// (512 B contiguous per wave store, L2 write-back absorbs the drain).
// ai row per iteration via wave-uniform pointer -> s_load (32 data SGPRs +
// 32 W2 SGPRs fits the 102-SGPR budget). 4 independent acc chains.
// ---------------------------------------------------------------------------
__global__ __launch_bounds__(256) void bias_kernel(
    const float* __restrict__ ai, const float* __restrict__ aj,
    const float* __restrict__ ae, const float* __restrict__ W2,
    const float* __restrict__ b2p, float* __restrict__ out)
{
    __shared__ float ae_lds[(TAU_ + 1) * AEP_];

    const int b    = blockIdx.z;
    const int i0   = blockIdx.y * 64;
    const int j0   = blockIdx.x * JT_;
    const int tid  = threadIdx.x;
    const int lane = tid & 63;
    const int w    = __builtin_amdgcn_readfirstlane(tid >> 6);
    const int jp   = j0 + lane * 2;

    const bool c0  = (j0 >= i0 + 64);          // dt == 0 over whole tile
    const bool c64 = (i0 >= j0 + JT_ + 64);    // dt == 64 over whole tile
    const bool constpath = c0 || c64;

    const float b2 = *b2p;

    // Per-lane column vectors for the two owned j's.
    float r0[H_], r1[H_];
    {
        const float* ajr = aj + ((size_t)(b * L_ + jp)) * H_;
#pragma unroll
        for (int h = 0; h < H_; h += 4) {
            const float4 v0 = *(const float4*)(ajr + h);
            const float4 v1 = *(const float4*)(ajr + H_ + h);
            r0[h + 0] = v0.x; r0[h + 1] = v0.y; r0[h + 2] = v0.z; r0[h + 3] = v0.w;
            r1[h + 0] = v1.x; r1[h + 1] = v1.y; r1[h + 2] = v1.z; r1[h + 3] = v1.w;
        }
    }

    if (constpath) {
        const float* aec = ae + (c0 ? 0 : TAU_) * H_;   // uniform -> s_load
#pragma unroll
        for (int h = 0; h < H_; ++h) {
            const float e = aec[h];
            r0[h] += e; r1[h] += e;
        }
    } else {
        for (int k = tid; k < (TAU_ + 1) * H_; k += 256)
            ae_lds[(k >> 5) * AEP_ + (k & 31)] = ae[k];
        __syncthreads();   // block-uniform branch
    }

    const float* aiBase = ai + ((size_t)(b * L_ + i0 + w * 16)) * H_;
    float* outb = out + ((size_t)b) * L_ * L_ + ((size_t)(i0 + w * 16)) * L_ + jp;

    if (constpath) {
        const float pc = b2 - 0.2f * (c0 ? 0.f : (float)TAU_);
        for (int ii = 0; ii < 16; ++ii) {
            const float* ar = aiBase + ii * H_;          // uniform -> s_load
            float ax = 0.f, ay = 0.f, bx = 0.f, by = 0.f;
#pragma unroll
            for (int h = 0; h < H_; h += 2) {
                const float w0 = W2[h], w1 = W2[h + 1];  // uniform -> sgpr
                const float a0 = ar[h], a1 = ar[h + 1];
                ax = fmaf(fmaxf(a0 + r0[h + 0], 0.f), w0, ax);
                ay = fmaf(fmaxf(a1 + r0[h + 1], 0.f), w1, ay);
                bx = fmaf(fmaxf(a0 + r1[h + 0], 0.f), w0, bx);
                by = fmaf(fmaxf(a1 + r1[h + 1], 0.f), w1, by);
            }
            const float2 o = make_float2(ax + ay + pc, bx + by + pc);
            *(float2*)(outb + (size_t)ii * L_) = o;      // plain store -> L2
        }
    } else {
        for (int ii = 0; ii < 16; ++ii) {
            const int i   = i0 + w * 16 + ii;
            const int d0  = i - jp;
            const int d1  = d0 - 1;
            const int dt0 = d0 < 0 ? 0 : (d0 > TAU_ ? TAU_ : d0);
            const int dt1 = d1 < 0 ? 0 : (d1 > TAU_ ? TAU_ : d1);
            const float* e0 = &ae_lds[dt0 * AEP_];
            const float* e1 = &ae_lds[dt1 * AEP_];
            const float* ar = aiBase + ii * H_;
            float ax = 0.f, ay = 0.f, bx = 0.f, by = 0.f;
#pragma unroll
            for (int h = 0; h < H_; h += 2) {
                const float w0 = W2[h], w1 = W2[h + 1];
                const float a0 = ar[h], a1 = ar[h + 1];
                ax = fmaf(fmaxf(a0 + r0[h + 0] + e0[h + 0], 0.f), w0, ax);
                ay = fmaf(fmaxf(a1 + r0[h + 1] + e0[h + 1], 0.f), w1, ay);
                bx = fmaf(fmaxf(a0 + r1[h + 0] + e1[h + 0], 0.f), w0, bx);
                by = fmaf(fmaxf(a1 + r1[h + 1] + e1[h + 1], 0.f), w1, by);
            }
            const float2 o = make_float2(ax + ay + b2 - 0.2f * (float)dt0,
                                         bx + by + b2 - 0.2f * (float)dt1);
            *(float2*)(outb + (size_t)ii * L_) = o;
        }
    }
}

extern "C" void kernel_launch(void* const* d_in, const int* in_sizes, int n_in,
                              void* d_out, int out_size, void* d_ws, size_t ws_size,
                              hipStream_t stream) {
    const float* x   = (const float*)d_in[0];
    const float* dtt = (const float*)d_in[1];
    const float* W1  = (const float*)d_in[2];
    const float* b1  = (const float*)d_in[3];
    const float* W2  = (const float*)d_in[4];
    const float* b2  = (const float*)d_in[5];
    float* out = (float*)d_out;

    float* ws = (float*)d_ws;
    float* ai = ws;                          // B*L*H floats
    float* aj = ws + B_ * L_ * H_;           // B*L*H floats
    float* ae = ws + 2 * B_ * L_ * H_;       // 65*H floats

    const int total  = B_ * L_ * H_ + (TAU_ + 1) * H_;
    const int blocks = (total + 255) / 256;
    hipLaunchKernelGGL(precompute_kernel, dim3(blocks), dim3(256), 0, stream,
                       x, dtt, W1, b1, ai, aj, ae);

    dim3 grid(L_ / JT_, L_ / 64, B_);
    hipLaunchKernelGGL(bias_kernel, grid, dim3(256), 0, stream,
                       ai, aj, ae, W2, b2, out);
}

// Round 6
// 28.922 us; speedup vs baseline: 1.3472x; 1.3472x over previous
//
#include <hip/hip_runtime.h>

#define B_   4
#define L_   1024
#define D_   16
#define H_   32
#define TAU_ 64
#define EMB_ 8
#define AEP_ 34   // ae_lds stride: even -> 8B-aligned float2 reads, 2-way banks (free)

typedef float f2 __attribute__((ext_vector_type(2)));

// ---------------------------------------------------------------------------
// Kernel 1: precompute
//   ai[b,l,h] = x[b,l,:] @ W1[0:16, h]
//   aj[b,l,h] = x[b,l,:] @ W1[16:32, h]
//   ae[t,h]   = dt_table[t,:] @ W1[32:40, h] + b1[h]
// ---------------------------------------------------------------------------
__global__ __launch_bounds__(256) void precompute_kernel(
    const float* __restrict__ x, const float* __restrict__ dtt,
    const float* __restrict__ W1, const float* __restrict__ b1,
    float* __restrict__ ai, float* __restrict__ aj, float* __restrict__ ae)
{
    const int id = blockIdx.x * 256 + threadIdx.x;
    const int NA = B_ * L_ * H_;
    if (id < NA) {
        const int h   = id & (H_ - 1);
        const int row = id >> 5;                 // b*L + l
        const float4* xr4 = (const float4*)(x + row * D_);
        const float4 v0 = xr4[0], v1 = xr4[1], v2 = xr4[2], v3 = xr4[3];
        const float xv[D_] = {v0.x, v0.y, v0.z, v0.w, v1.x, v1.y, v1.z, v1.w,
                              v2.x, v2.y, v2.z, v2.w, v3.x, v3.y, v3.z, v3.w};
        float s1 = 0.f, s2 = 0.f;
#pragma unroll
        for (int d = 0; d < D_; ++d) {
            s1 = fmaf(xv[d], W1[d * H_ + h], s1);
            s2 = fmaf(xv[d], W1[(D_ + d) * H_ + h], s2);
        }
        ai[id] = s1;
        aj[id] = s2;
    } else {
        const int k = id - NA;
        if (k < (TAU_ + 1) * H_) {
            const int h = k & (H_ - 1);
            const int t = k >> 5;
            float s = b1[h];
#pragma unroll
            for (int e = 0; e < EMB_; ++e)
                s = fmaf(dtt[t * EMB_ + e], W1[(2 * D_ + e) * H_ + h], s);
            ae[k] = s;
        }
    }
}

// ---------------------------------------------------------------------------
// Kernel 2: bias kernel, packed-f32 edition (R3 base + VOP3P inner loop).
// Tile 64x64, 256 thr = 4 waves; lane = j (NT dword stores, coalesced);
// wave w owns rows i0+w*16..+15 via wave-uniform s_load pointers.
// Inner loop in ext_vector float2: v_pk_add / v_pk_max / v_pk_fma_f32
// -> ~52 VALU instrs per output instead of 96.
// ---------------------------------------------------------------------------
__global__ __launch_bounds__(256, 4) void bias_kernel(
    const float* __restrict__ ai, const float* __restrict__ aj,
    const float* __restrict__ ae, const float* __restrict__ W2,
    const float* __restrict__ b2p, float* __restrict__ out)
{
    __shared__ float ae_lds[(TAU_ + 1) * AEP_];

    const int b    = blockIdx.z;
    const int i0   = blockIdx.y * 64;
    const int j0   = blockIdx.x * 64;
    const int tid  = threadIdx.x;
    const int lane = tid & 63;
    const int w    = __builtin_amdgcn_readfirstlane(tid >> 6);
    const int j    = j0 + lane;

    const bool c0  = (j0 >= i0 + 64);          // dt == 0 over whole tile
    const bool c64 = (i0 >= j0 + 128);         // dt == 64 over whole tile
    const bool constpath = c0 || c64;

    const float b2 = *b2p;

    // Per-lane column vector r2[h/2] = aj[j, h..h+1] (+ ae row on const path).
    f2 r2[H_ / 2];
    {
        const float* ajr = aj + ((size_t)(b * L_ + j)) * H_;
#pragma unroll
        for (int h = 0; h < H_; h += 4) {
            const float4 v = *(const float4*)(ajr + h);
            r2[(h >> 1) + 0] = (f2){v.x, v.y};
            r2[(h >> 1) + 1] = (f2){v.z, v.w};
        }
    }

    if (constpath) {
        const float* aec = ae + (c0 ? 0 : TAU_) * H_;   // uniform -> s_load
#pragma unroll
        for (int h = 0; h < H_; h += 2) {
            const f2 e = {aec[h], aec[h + 1]};
            r2[h >> 1] += e;
        }
    } else {
        for (int k = tid; k < (TAU_ + 1) * H_; k += 256)
            ae_lds[(k >> 5) * AEP_ + (k & 31)] = ae[k];
        __syncthreads();   // block-uniform branch
    }

    const float* aiBase = ai + ((size_t)(b * L_ + i0 + w * 16)) * H_;
    float* outb = out + ((size_t)b) * L_ * L_ + ((size_t)(i0 + w * 16)) * L_ + j;
    const f2 z2 = {0.f, 0.f};

    if (constpath) {
        const float pc = b2 - 0.2f * (c0 ? 0.f : (float)TAU_);
        for (int ii = 0; ii < 16; ii += 2) {
            const float* ar0 = aiBase + (ii + 0) * H_;   // uniform -> s_load
            const float* ar1 = aiBase + (ii + 1) * H_;
            f2 acc0 = z2, acc1 = z2;
#pragma unroll
            for (int h = 0; h < H_; h += 2) {
                const f2 wv = {W2[h], W2[h + 1]};        // sgpr pair
                const f2 a0 = {ar0[h], ar0[h + 1]};      // sgpr pair
                const f2 a1 = {ar1[h], ar1[h + 1]};
                f2 p0 = a0 + r2[h >> 1];                 // v_pk_add_f32
                f2 p1 = a1 + r2[h >> 1];
                p0 = __builtin_elementwise_max(p0, z2);  // v_pk_max_f32
                p1 = __builtin_elementwise_max(p1, z2);
                acc0 = __builtin_elementwise_fma(p0, wv, acc0);  // v_pk_fma_f32
                acc1 = __builtin_elementwise_fma(p1, wv, acc1);
            }
            __builtin_nontemporal_store(acc0.x + acc0.y + pc, outb + (size_t)(ii + 0) * L_);
            __builtin_nontemporal_store(acc1.x + acc1.y + pc, outb + (size_t)(ii + 1) * L_);
        }
    } else {
        for (int ii = 0; ii < 16; ++ii) {
            const int i   = i0 + w * 16 + ii;
            const int d   = i - j;
            const int dt  = d < 0 ? 0 : (d > TAU_ ? TAU_ : d);
            const f2* eL  = (const f2*)&ae_lds[dt * AEP_];   // 8B aligned
            const float* ar = aiBase + ii * H_;
            f2 acc = z2;
#pragma unroll
            for (int h = 0; h < H_; h += 2) {
                const f2 wv = {W2[h], W2[h + 1]};
                const f2 a  = {ar[h], ar[h + 1]};
                f2 p = a + r2[h >> 1];
                p = p + eL[h >> 1];
                p = __builtin_elementwise_max(p, z2);
                acc = __builtin_elementwise_fma(p, wv, acc);
            }
            __builtin_nontemporal_store(acc.x + acc.y + b2 - 0.2f * (float)dt,
                                        outb + (size_t)ii * L_);
        }
    }
}

extern "C" void kernel_launch(void* const* d_in, const int* in_sizes, int n_in,
                              void* d_out, int out_size, void* d_ws, size_t ws_size,
                              hipStream_t stream) {
    const float* x   = (const float*)d_in[0];
    const float* dtt = (const float*)d_in[1];
    const float* W1  = (const float*)d_in[2];
    const float* b1  = (const float*)d_in[3];
    const float* W2  = (const float*)d_in[4];
    const float* b2  = (const float*)d_in[5];
    float* out = (float*)d_out;

    float* ws = (float*)d_ws;
    float* ai = ws;                          // B*L*H floats
    float* aj = ws + B_ * L_ * H_;           // B*L*H floats
    float* ae = ws + 2 * B_ * L_ * H_;       // 65*H floats

    const int total  = B_ * L_ * H_ + (TAU_ + 1) * H_;
    const int blocks = (total + 255) / 256;
    hipLaunchKernelGGL(precompute_kernel, dim3(blocks), dim3(256), 0, stream,
                       x, dtt, W1, b1, ai, aj, ae);

    dim3 grid(L_ / 64, L_ / 64, B_);
    hipLaunchKernelGGL(bias_kernel, grid, dim3(256), 0, stream,
                       ai, aj, ae, W2, b2, out);
}